// Round 1
// 2225.536 us; speedup vs baseline: 1.0427x; 1.0427x over previous
//
#include <hip/hip_runtime.h>
#include <math.h>

// Problem constants
#define Qn 2048
#define Nn 64
#define Sn 128
#define An 4
#define En 128
#define TASKW 576  // N + 4*S
#define NEGV -1000000000.0f

// ---------------------------------------------------------------------------
// Packed fp32 math (v_pk_fma_f32: 2 x f32 per lane per issue; this is how
// gfx950 reaches its 157.3 TF fp32 rate -- scalar v_fma_f32 is half rate).
// ---------------------------------------------------------------------------
typedef float v2f __attribute__((ext_vector_type(2)));

__device__ __forceinline__ v2f mkv2(float a, float b) {
  v2f r; r.x = a; r.y = b; return r;
}
__device__ __forceinline__ void pkfma(v2f& d, v2f a, v2f b) {
  // d = a * b + d (elementwise)
  asm("v_pk_fma_f32 %0, %1, %2, %0" : "+v"(d) : "v"(a), "v"(b));
}
__device__ __forceinline__ v2f pkmul(v2f a, v2f b) {
  v2f d; asm("v_pk_mul_f32 %0, %1, %2" : "=v"(d) : "v"(a), "v"(b)); return d;
}
__device__ __forceinline__ v2f pkadd(v2f a, v2f b) {
  v2f d; asm("v_pk_add_f32 %0, %1, %2" : "=v"(d) : "v"(a), "v"(b)); return d;
}

// ---------------------------------------------------------------------------
// Threefry-2x32 (20 rounds), matches JAX's threefry2x32_p exactly.
// ---------------------------------------------------------------------------
__device__ __forceinline__ void threefry2x32(unsigned k0, unsigned k1,
                                             unsigned x0, unsigned x1,
                                             unsigned& o0, unsigned& o1) {
  unsigned ks2 = k0 ^ k1 ^ 0x1BD11BDAu;
  x0 += k0; x1 += k1;
#define TFR(r) { x0 += x1; x1 = (x1 << (r)) | (x1 >> (32 - (r))); x1 ^= x0; }
  TFR(13) TFR(15) TFR(26) TFR(6)
  x0 += k1;  x1 += ks2 + 1u;
  TFR(17) TFR(29) TFR(16) TFR(24)
  x0 += ks2; x1 += k0 + 2u;
  TFR(13) TFR(15) TFR(26) TFR(6)
  x0 += k0;  x1 += k1 + 3u;
  TFR(17) TFR(29) TFR(16) TFR(24)
  x0 += k1;  x1 += ks2 + 4u;
  TFR(13) TFR(15) TFR(26) TFR(6)
  x0 += ks2; x1 += k0 + 5u;
#undef TFR
  o0 = x0; o1 = x1;
}

__device__ __forceinline__ float silu_f(float x) {
  return x / (1.0f + expf(-x));
}

// Fast-math helpers (v_exp_f32 / v_log_f32 / v_rcp_f32; ~1 ulp)
__device__ __forceinline__ float fexp(float x) {
  return __builtin_amdgcn_exp2f(x * 1.44269504088896f);
}
__device__ __forceinline__ float fsilu(float x) {
  const float e = __builtin_amdgcn_exp2f(x * -1.44269504088896f);
  return x * __builtin_amdgcn_rcpf(1.0f + e);
}
__device__ __forceinline__ float flog(float x) {
  return __builtin_amdgcn_logf(x) * 0.69314718055995f;
}

// ---------------------------------------------------------------------------
// Setup: M = w_node2 @ w_ser2^T, dvec fold, PRNG keys
// ---------------------------------------------------------------------------
__global__ void setup_kernel(const float* __restrict__ w_node2,
                             const float* __restrict__ b_node2,
                             const float* __restrict__ w_ser2,
                             const float* __restrict__ b_ser2,
                             float* __restrict__ Mbuf, float* __restrict__ dvec,
                             unsigned* __restrict__ keys) {
  const int b = blockIdx.x, t = threadIdx.x;
  if (b < 128) {
    float acc = 0.0f;
    for (int e = 0; e < 128; ++e)
      acc = fmaf(w_node2[b * 128 + e], w_ser2[t * 128 + e], acc);
    Mbuf[b * 128 + t] = acc;
  } else if (b == 128) {
    float acc = 0.0f;
    for (int e = 0; e < 128; ++e)
      acc = fmaf(b_node2[e], w_ser2[t * 128 + e], acc);
    dvec[t] = acc;
  } else {
    if (t < 64) {
      unsigned o0, o1;
      threefry2x32(0u, 1u, 0u, (unsigned)t, o0, o1);
      keys[2 * t + 0] = o0;
      keys[2 * t + 1] = o1;
    }
  }
}

// ---------------------------------------------------------------------------
// K1: node_emb = silu(concat(tasks[:,:, :64], cons) @ w1 + b1) @ w2 + b2
// ---------------------------------------------------------------------------
__global__ __launch_bounds__(256, 2)
void init_mlp_kernel(const float* __restrict__ tasks,
                     const float* __restrict__ cons,
                     const float* __restrict__ w1, const float* __restrict__ b1,
                     const float* __restrict__ w2, const float* __restrict__ b2,
                     float* __restrict__ node_emb) {
  const int q = blockIdx.x, tid = threadIdx.x;
  const int lane = tid & 127, half = tid >> 7;
  __shared__ __align__(16) float xr[2][68];
  __shared__ __align__(16) float sgb[2][128];
  v2f w1p[34], w2p[64];
#pragma unroll
  for (int i = 0; i < 34; ++i)
    w1p[i] = mkv2(w1[(2 * i) * 128 + lane], w1[(2 * i + 1) * 128 + lane]);
#pragma unroll
  for (int j = 0; j < 64; ++j)
    w2p[j] = mkv2(w2[(2 * j) * 128 + lane], w2[(2 * j + 1) * 128 + lane]);
  const float bb1 = b1[lane], bb2 = b2[lane];
  for (int r = 0; r < 64; r += 2) {
    if (tid < 136) {
      const int rr = tid / 68, j = tid - rr * 68;
      xr[rr][j] = (j < 64) ? tasks[(q * 64 + r + rr) * TASKW + j]
                           : cons[q * 4 + (j - 64)];
    }
    __syncthreads();
    v2f gp = mkv2(0.0f, 0.0f);
    const v2f* xr2 = (const v2f*)&xr[half][0];
#pragma unroll
    for (int i = 0; i < 34; ++i) pkfma(gp, xr2[i], w1p[i]);
    const float g = gp.x + gp.y + bb1;
    sgb[half][lane] = silu_f(g);
    __syncthreads();
    v2f op = mkv2(0.0f, 0.0f);
    const v2f* sgb2 = (const v2f*)&sgb[half][0];
#pragma unroll
    for (int j = 0; j < 64; ++j) pkfma(op, sgb2[j], w2p[j]);
    node_emb[(q * 64 + r + half) * 128 + lane] = op.x + op.y + bb2;
    __syncthreads();
  }
}

// ---------------------------------------------------------------------------
// K2: fused MHA (QKV + scores + softmax + AV), packed-f32 inner loops
// ---------------------------------------------------------------------------
__global__ __launch_bounds__(256, 2)
void mha_kernel(const float* __restrict__ node_emb,
                const float* __restrict__ wq, const float* __restrict__ bq,
                const float* __restrict__ wk, const float* __restrict__ bk,
                const float* __restrict__ wv, const float* __restrict__ bv,
                float* __restrict__ y_out) {
  const int q = blockIdx.x, tid = threadIdx.x;
  __shared__ __align__(16) float xs[64][130];
  __shared__ __align__(16) float qh[64][18];
  __shared__ __align__(16) float kh[64][18];
  __shared__ __align__(16) float vt[16][66];
  __shared__ __align__(16) float pool[3 * 16 * 130];  // wht[3][16][130] U at[64][66]
  float (*wht)[16][130] = (float (*)[16][130])pool;
  float (*at)[66] = (float (*)[66])pool;

  for (int idx = tid; idx < 64 * 128; idx += 256) {
    const int n = idx >> 7, e = idx & 127;
    xs[n][e] = node_emb[(q * 64 + n) * 128 + e];
  }
  __syncthreads();

  const int d16 = tid >> 4;  // 0..15
  const int ng = tid & 15;   // 0..15

  for (int hd = 0; hd < 8; ++hd) {
    for (int idx = tid; idx < 3 * 128 * 16; idx += 256) {
      const int m = idx >> 11, k = (idx >> 4) & 127, d = idx & 15;
      const float* W = (m == 0) ? wq : (m == 1) ? wk : wv;
      wht[m][d][k] = W[k * 128 + hd * 16 + d];
    }
    __syncthreads();

    {
      const float bqv = bq[hd * 16 + d16];
      const float bkv = bk[hd * 16 + d16];
      const float bvv = bv[hd * 16 + d16];
      const v2f* wq2 = (const v2f*)&wht[0][d16][0];
      const v2f* wk2 = (const v2f*)&wht[1][d16][0];
      const v2f* wv2 = (const v2f*)&wht[2][d16][0];
      const v2f* xr0 = (const v2f*)&xs[ng][0];
      const v2f* xr1 = (const v2f*)&xs[ng + 16][0];
      const v2f* xr2 = (const v2f*)&xs[ng + 32][0];
      const v2f* xr3 = (const v2f*)&xs[ng + 48][0];
      v2f aq0 = mkv2(0, 0), aq1 = mkv2(0, 0), aq2 = mkv2(0, 0), aq3 = mkv2(0, 0);
      v2f ak0 = mkv2(0, 0), ak1 = mkv2(0, 0), ak2 = mkv2(0, 0), ak3 = mkv2(0, 0);
      v2f av0 = mkv2(0, 0), av1 = mkv2(0, 0), av2 = mkv2(0, 0), av3 = mkv2(0, 0);
#pragma unroll 8
      for (int kk = 0; kk < 64; ++kk) {
        const v2f wqv = wq2[kk], wkv = wk2[kk], wvv = wv2[kk];
        const v2f x0 = xr0[kk], x1 = xr1[kk], x2 = xr2[kk], x3 = xr3[kk];
        pkfma(aq0, x0, wqv); pkfma(aq1, x1, wqv);
        pkfma(aq2, x2, wqv); pkfma(aq3, x3, wqv);
        pkfma(ak0, x0, wkv); pkfma(ak1, x1, wkv);
        pkfma(ak2, x2, wkv); pkfma(ak3, x3, wkv);
        pkfma(av0, x0, wvv); pkfma(av1, x1, wvv);
        pkfma(av2, x2, wvv); pkfma(av3, x3, wvv);
      }
      qh[ng][d16] = fmaxf(aq0.x + aq0.y + bqv, 0.0f);
      qh[ng + 16][d16] = fmaxf(aq1.x + aq1.y + bqv, 0.0f);
      qh[ng + 32][d16] = fmaxf(aq2.x + aq2.y + bqv, 0.0f);
      qh[ng + 48][d16] = fmaxf(aq3.x + aq3.y + bqv, 0.0f);
      kh[ng][d16] = fmaxf(ak0.x + ak0.y + bkv, 0.0f);
      kh[ng + 16][d16] = fmaxf(ak1.x + ak1.y + bkv, 0.0f);
      kh[ng + 32][d16] = fmaxf(ak2.x + ak2.y + bkv, 0.0f);
      kh[ng + 48][d16] = fmaxf(ak3.x + ak3.y + bkv, 0.0f);
      vt[d16][ng] = fmaxf(av0.x + av0.y + bvv, 0.0f);
      vt[d16][ng + 16] = fmaxf(av1.x + av1.y + bvv, 0.0f);
      vt[d16][ng + 32] = fmaxf(av2.x + av2.y + bvv, 0.0f);
      vt[d16][ng + 48] = fmaxf(av3.x + av3.y + bvv, 0.0f);
    }
    __syncthreads();

    {
      const int n = tid >> 2, mg = tid & 3;
      v2f qv[8];
      const v2f* qrow = (const v2f*)&qh[n][0];
#pragma unroll
      for (int kk = 0; kk < 8; ++kk) qv[kk] = qrow[kk];
#pragma unroll 4
      for (int jj = 0; jj < 16; ++jj) {
        const int m = mg + 4 * jj;
        const v2f* krow = (const v2f*)&kh[m][0];
        v2f accp = mkv2(0.0f, 0.0f);
#pragma unroll
        for (int kk = 0; kk < 8; ++kk) pkfma(accp, qv[kk], krow[kk]);
        at[n][m] = (accp.x + accp.y) * 0.25f;
      }
    }
    __syncthreads();

    {
      const int r = tid >> 2, p = tid & 3;
      float mx = -1e30f;
#pragma unroll
      for (int t2 = 0; t2 < 16; ++t2) mx = fmaxf(mx, at[r][p * 16 + t2]);
      mx = fmaxf(mx, __shfl_xor(mx, 1, 64));
      mx = fmaxf(mx, __shfl_xor(mx, 2, 64));
      float s = 0.0f;
#pragma unroll
      for (int t2 = 0; t2 < 16; ++t2) {
        const float e = fexp(at[r][p * 16 + t2] - mx);
        at[r][p * 16 + t2] = e;
        s += e;
      }
      s += __shfl_xor(s, 1, 64);
      s += __shfl_xor(s, 2, 64);
      const float rs = __builtin_amdgcn_rcpf(s);
#pragma unroll
      for (int t2 = 0; t2 < 16; ++t2) at[r][p * 16 + t2] *= rs;
    }
    __syncthreads();

    {
      const int dd = tid & 15, ngr = tid >> 4;
      const v2f* vrow = (const v2f*)&vt[dd][0];
      const v2f* ar0 = (const v2f*)&at[ngr][0];
      const v2f* ar1 = (const v2f*)&at[ngr + 16][0];
      const v2f* ar2 = (const v2f*)&at[ngr + 32][0];
      const v2f* ar3 = (const v2f*)&at[ngr + 48][0];
      v2f ac0 = mkv2(0, 0), ac1 = mkv2(0, 0), ac2 = mkv2(0, 0), ac3 = mkv2(0, 0);
#pragma unroll 8
      for (int kk = 0; kk < 32; ++kk) {
        const v2f vv = vrow[kk];
        pkfma(ac0, ar0[kk], vv);
        pkfma(ac1, ar1[kk], vv);
        pkfma(ac2, ar2[kk], vv);
        pkfma(ac3, ar3[kk], vv);
      }
      y_out[(q * 64 + ngr) * 128 + hd * 16 + dd] = ac0.x + ac0.y;
      y_out[(q * 64 + ngr + 16) * 128 + hd * 16 + dd] = ac1.x + ac1.y;
      y_out[(q * 64 + ngr + 32) * 128 + hd * 16 + dd] = ac2.x + ac2.y;
      y_out[(q * 64 + ngr + 48) * 128 + hd * 16 + dd] = ac3.x + ac3.y;
    }
    __syncthreads();
  }
}

// ---------------------------------------------------------------------------
// K3: nodes_emb = relu(y @ wo + bo) + node_emb   (LDS-tiled, packed f32)
// ---------------------------------------------------------------------------
__global__ __launch_bounds__(256, 4)
void outproj_kernel(const float* __restrict__ node_emb,
                    const float* __restrict__ wo, const float* __restrict__ bo,
                    float* __restrict__ nodes_emb) {
  const int q = blockIdx.x, tid = threadIdx.x;
  __shared__ __align__(16) float ys[64][130];
  __shared__ __align__(16) float wot[32][130];
  for (int idx = tid; idx < 64 * 128; idx += 256) {
    const int n = idx >> 7, e = idx & 127;
    ys[n][e] = nodes_emb[(q * 64 + n) * 128 + e];
  }
  const int cg = tid & 15, ngr = tid >> 4;
  for (int c0 = 0; c0 < 128; c0 += 32) {
    __syncthreads();
    for (int idx = tid; idx < 32 * 128; idx += 256) {
      const int k = idx >> 5, c = idx & 31;
      wot[c][k] = wo[k * 128 + c0 + c];
    }
    __syncthreads();
    const int c = c0 + 2 * cg;
    const v2f* w0 = (const v2f*)&wot[2 * cg][0];
    const v2f* w1 = (const v2f*)&wot[2 * cg + 1][0];
    const v2f* yr0 = (const v2f*)&ys[ngr][0];
    const v2f* yr1 = (const v2f*)&ys[ngr + 16][0];
    const v2f* yr2 = (const v2f*)&ys[ngr + 32][0];
    const v2f* yr3 = (const v2f*)&ys[ngr + 48][0];
    v2f a00 = mkv2(0, 0), a01 = mkv2(0, 0), a10 = mkv2(0, 0), a11 = mkv2(0, 0);
    v2f a20 = mkv2(0, 0), a21 = mkv2(0, 0), a30 = mkv2(0, 0), a31 = mkv2(0, 0);
#pragma unroll 8
    for (int kk = 0; kk < 64; ++kk) {
      const v2f wv0 = w0[kk], wv1 = w1[kk];
      const v2f x0 = yr0[kk], x1 = yr1[kk], x2 = yr2[kk], x3 = yr3[kk];
      pkfma(a00, x0, wv0); pkfma(a01, x0, wv1);
      pkfma(a10, x1, wv0); pkfma(a11, x1, wv1);
      pkfma(a20, x2, wv0); pkfma(a21, x2, wv1);
      pkfma(a30, x3, wv0); pkfma(a31, x3, wv1);
    }
    const float b0v = bo[c], b1v = bo[c + 1];
#define OUTP_EMIT(J, A0, A1)                                                  \
    {                                                                         \
      const int n = ngr + 16 * J;                                             \
      const float2 res = *(const float2*)&node_emb[(q * 64 + n) * 128 + c];   \
      float2 o;                                                               \
      o.x = fmaxf(A0.x + A0.y + b0v, 0.0f) + res.x;                           \
      o.y = fmaxf(A1.x + A1.y + b1v, 0.0f) + res.y;                           \
      *(float2*)&nodes_emb[(q * 64 + n) * 128 + c] = o;                       \
    }
    OUTP_EMIT(0, a00, a01)
    OUTP_EMIT(1, a10, a11)
    OUTP_EMIT(2, a20, a21)
    OUTP_EMIT(3, a30, a31)
#undef OUTP_EMIT
  }
}

// ---------------------------------------------------------------------------
// K3b: gbase[q,n,e] = sum_j nodes_emb[q,n,j]*w_node1[j,e] + b_node1[e]
// ---------------------------------------------------------------------------
__global__ __launch_bounds__(256, 4)
void gbase_kernel(const float* __restrict__ nodes_emb,
                  const float* __restrict__ w_node1,
                  const float* __restrict__ b_node1,
                  float* __restrict__ gbase) {
  const int q = blockIdx.x, tid = threadIdx.x;
  __shared__ __align__(16) float ys[64][130];
  __shared__ __align__(16) float wot[32][130];
  for (int idx = tid; idx < 64 * 128; idx += 256) {
    const int n = idx >> 7, e = idx & 127;
    ys[n][e] = nodes_emb[(q * 64 + n) * 128 + e];
  }
  const int cg = tid & 15, ngr = tid >> 4;
  for (int c0 = 0; c0 < 128; c0 += 32) {
    __syncthreads();
    for (int idx = tid; idx < 32 * 128; idx += 256) {
      const int k = idx >> 5, c = idx & 31;
      wot[c][k] = w_node1[k * 128 + c0 + c];
    }
    __syncthreads();
    const int c = c0 + 2 * cg;
    const v2f* w0 = (const v2f*)&wot[2 * cg][0];
    const v2f* w1 = (const v2f*)&wot[2 * cg + 1][0];
    const v2f* yr0 = (const v2f*)&ys[ngr][0];
    const v2f* yr1 = (const v2f*)&ys[ngr + 16][0];
    const v2f* yr2 = (const v2f*)&ys[ngr + 32][0];
    const v2f* yr3 = (const v2f*)&ys[ngr + 48][0];
    v2f a00 = mkv2(0, 0), a01 = mkv2(0, 0), a10 = mkv2(0, 0), a11 = mkv2(0, 0);
    v2f a20 = mkv2(0, 0), a21 = mkv2(0, 0), a30 = mkv2(0, 0), a31 = mkv2(0, 0);
#pragma unroll 8
    for (int kk = 0; kk < 64; ++kk) {
      const v2f wv0 = w0[kk], wv1 = w1[kk];
      const v2f x0 = yr0[kk], x1 = yr1[kk], x2 = yr2[kk], x3 = yr3[kk];
      pkfma(a00, x0, wv0); pkfma(a01, x0, wv1);
      pkfma(a10, x1, wv0); pkfma(a11, x1, wv1);
      pkfma(a20, x2, wv0); pkfma(a21, x2, wv1);
      pkfma(a30, x3, wv0); pkfma(a31, x3, wv1);
    }
    const float b0v = b_node1[c], b1v = b_node1[c + 1];
#define GB_EMIT(J, A0, A1)                                                    \
    {                                                                         \
      const int n = ngr + 16 * J;                                             \
      float2 o;                                                               \
      o.x = A0.x + A0.y + b0v;                                                \
      o.y = A1.x + A1.y + b1v;                                                \
      *(float2*)&gbase[(q * 64 + n) * 128 + c] = o;                           \
    }
    GB_EMIT(0, a00, a01)
    GB_EMIT(1, a10, a11)
    GB_EMIT(2, a20, a21)
    GB_EMIT(3, a30, a31)
#undef GB_EMIT
  }
}

// ---------------------------------------------------------------------------
// K4: 64-step scan, one workgroup per q.
// New: (a) ballot-compaction of active services (mask==0 entries are exactly
// dropped: they contribute 0 to softmax and never win gumbel-argmax), heavy
// SiLU-logits loop runs only over na (~64) active services with 4 threads
// per service; (b) packed v_pk_fma_f32 in the matvec and logits dot;
// (c) threefry/gumbel only for active services (same per-(q,s) counters ->
// bit-identical sampling). Weight/uu pair tables stored in permuted slots
// slot(j)=((j&15)<<2)|(j>>4) so the 4 h-quarter lanes read consecutive
// addresses (bank-conflict-free broadcast).
// ---------------------------------------------------------------------------
__global__ __launch_bounds__(256, 4)
void scan_kernel(const float* __restrict__ tasks, const int* __restrict__ masks,
                 const int* __restrict__ topologicals,
                 const float* __restrict__ w_node1,
                 const float* __restrict__ w_ser1,
                 const float* __restrict__ b_ser1,
                 const float* __restrict__ gbase,
                 const float* __restrict__ Mbuf, const float* __restrict__ dvec,
                 const unsigned* __restrict__ keys, float* __restrict__ out) {
  const int q = blockIdx.x, tid = threadIdx.x;
  const int lane = tid & 127, half = tid >> 7;
  const int wl = tid & 63;   // lane within wave
  const int wave = tid >> 6;

  __shared__ __align__(16) float task_s[2][TASKW];
  __shared__ __align__(16) float gb_s[2][128];
  __shared__ int mask_s[2][128];
  __shared__ int topo_s[64];
  __shared__ __align__(16) float sg[128];
  __shared__ __align__(16) v2f warr_s[64][4];  // w_ser1 pairs, slot-permuted
  __shared__ __align__(16) v2f bp_s[64];       // b_ser1 pairs, slot-permuted
  __shared__ __align__(16) v2f up_s[64];       // uu pairs, slot-permuted
  __shared__ __align__(16) float red[256];
  __shared__ float lcomp_s[128];  // logits, compact (active) order
  __shared__ float gla_s[128];    // gumbel-perturbed, compact order
  __shared__ int act_s[128];      // active service indices
  __shared__ float qos_s[64 * 4];
  __shared__ float ridx_s[64], rprob_s[64];
  __shared__ __align__(16) float qw[4][128];  // w_node1 rows 128..131
  __shared__ __align__(16) float dvs[128];
  __shared__ float scal[2];  // 0:mx 1:sumexp
  __shared__ int sidx_s, kstar_s, na_s;
  __shared__ unsigned keys_s[128];

  v2f Mr2[32];
#pragma unroll
  for (int j = 0; j < 32; ++j)
    Mr2[j] = mkv2(Mbuf[(half * 64 + 2 * j) * 128 + lane],
                  Mbuf[(half * 64 + 2 * j + 1) * 128 + lane]);

  if (tid < 64) {
    topo_s[tid] = topologicals[q * 64 + tid];
    const int j = tid, sl = ((j & 15) << 2) | (j >> 4);
#pragma unroll
    for (int c = 0; c < 4; ++c)
      warr_s[sl][c] =
          mkv2(w_ser1[c * 128 + 2 * j], w_ser1[c * 128 + 2 * j + 1]);
    bp_s[sl] = mkv2(b_ser1[2 * j], b_ser1[2 * j + 1]);
  }
  if (tid < 128) {
    dvs[tid] = dvec[tid];
    keys_s[tid] = keys[tid];
  }
  for (int i = tid; i < 512; i += 256)
    qw[i >> 7][i & 127] = w_node1[(128 + (i >> 7)) * 128 + (i & 127)];
  if (tid < 64) {
    qos_s[tid * 4 + 0] = 3.0f;
    qos_s[tid * 4 + 1] = 1.0f;
    qos_s[tid * 4 + 2] = 0.0f;
    qos_s[tid * 4 + 3] = 1.0f;
    ridx_s[tid] = 0.0f;
    rprob_s[tid] = 0.0f;
  }
  float ava = 1.0f, tp = 3.0f, rel = 1.0f;  // per-thread redundant state
  __syncthreads();

  // Prologue: stage step 0 into buffer 0
  {
    const int topo0 = topo_s[63];
    if (tid < 144)
      ((float4*)task_s[0])[tid] =
          ((const float4*)(tasks + (size_t)(q * 64 + topo0) * TASKW))[tid];
    if (tid < 128) {
      gb_s[0][tid] = gbase[(q * 64 + topo0) * 128 + tid];
      mask_s[0][tid] = masks[(q * 64 + topo0) * 128 + tid];
    }
  }
  __syncthreads();

  for (int t = 0; t < 64; ++t) {
    const int cur = t & 1, nxt = cur ^ 1;
    const int topo = topo_s[63 - t];

    // Phase 1: waves 0/1 compute rt (needed by sg + state update);
    // wave 2 compacts the active-service list from the mask.
    float rt = 0.0f;
    if (wave < 2) {
      float p = task_s[cur][wl] * qos_s[wl * 4];
#pragma unroll
      for (int o = 32; o > 0; o >>= 1) p = fmaxf(p, __shfl_xor(p, o, 64));
      rt = p;
    } else if (wave == 2) {
      const int m0 = mask_s[cur][wl] != 0;
      const int m1 = mask_s[cur][wl + 64] != 0;
      const unsigned long long b0 = __ballot(m0);
      const unsigned long long b1 = __ballot(m1);
      const unsigned long long lt = (1ull << wl) - 1ull;
      const int c0 = __popcll(b0);
      if (m0) act_s[__popcll(b0 & lt)] = wl;
      if (m1) act_s[c0 + __popcll(b1 & lt)] = wl + 64;
      if (wl == 0) na_s = c0 + __popcll(b1);
    }
    if (tid < 128) {
      float g = gb_s[cur][tid];
      g = fmaf(rt, qw[0][tid], g);
      g = fmaf(ava, qw[1][tid], g);
      g = fmaf(tp, qw[2][tid], g);
      g = fmaf(rel, qw[3][tid], g);
      sg[tid] = fsilu(g);
    }
    __syncthreads();  // B_a : sg, act, na visible

    // u = silu(g) @ M + dvec (split partials, packed)
    {
      v2f accp = mkv2(0.0f, 0.0f);
      const v2f* sg2 = (const v2f*)sg + half * 32;
#pragma unroll
      for (int j = 0; j < 32; ++j) pkfma(accp, sg2[j], Mr2[j]);
      red[tid] = accp.x + accp.y;
    }
    __syncthreads();  // B_b
    if (tid < 64) {
      const v2f r0 = *(const v2f*)&red[2 * tid];
      const v2f r1 = *(const v2f*)&red[2 * tid + 128];
      const v2f dv = *(const v2f*)&dvs[2 * tid];
      up_s[((tid & 15) << 2) | (tid >> 4)] = pkadd(pkadd(r0, r1), dv);
    }
    __syncthreads();  // B_c : up visible

    // Prefetch next step's rows (issue early; lands in regs)
    float4 pf_task;
    float pf_gb;
    int pf_mask;
    {
      const int tn = (t < 63) ? t + 1 : 63;
      const int ntopo = topo_s[63 - tn];
      if (tid < 144)
        pf_task =
            ((const float4*)(tasks + (size_t)(q * 64 + ntopo) * TASKW))[tid];
      if (tid < 128) {
        pf_gb = gbase[(q * 64 + ntopo) * 128 + tid];
        pf_mask = masks[(q * 64 + ntopo) * 128 + tid];
      }
    }

    // Compact logits: 4 threads (h-quarters) per ACTIVE service only.
    const int na = na_s;
    {
      const int si = tid >> 2, hq = tid & 3;
      float ls[2];
#pragma unroll
      for (int rep = 0; rep < 2; ++rep) {
        const int slot = si + 64 * rep;
        float lv = 0.0f;
        if (slot < na) {
          const int s = act_s[slot];
          const float4 sv = *(const float4*)&task_s[cur][64 + 4 * s];
          const v2f svx = mkv2(sv.x, sv.x), svy = mkv2(sv.y, sv.y);
          const v2f svz = mkv2(sv.z, sv.z), svw = mkv2(sv.w, sv.w);
          v2f acc = mkv2(0.0f, 0.0f);
#pragma unroll
          for (int jj = 0; jj < 16; ++jj) {
            const int sl = (jj << 2) | hq;
            v2f p = bp_s[sl];
            pkfma(p, svx, warr_s[sl][0]);
            pkfma(p, svy, warr_s[sl][1]);
            pkfma(p, svz, warr_s[sl][2]);
            pkfma(p, svw, warr_s[sl][3]);
            const v2f e =
                pkmul(p, mkv2(-1.44269504088896f, -1.44269504088896f));
            const float ex = __builtin_amdgcn_exp2f(e.x);
            const float ey = __builtin_amdgcn_exp2f(e.y);
            const float rx = __builtin_amdgcn_rcpf(1.0f + ex);
            const float ry = __builtin_amdgcn_rcpf(1.0f + ey);
            pkfma(acc, mkv2(p.x * rx, p.y * ry), up_s[sl]);
          }
          lv = acc.x + acc.y;
        }
        // quad reduce (partners share the same predicate: si uniform in quad)
        lv += __shfl_xor(lv, 1, 64);
        lv += __shfl_xor(lv, 2, 64);
        ls[rep] = lv;
      }
      if (hq == 0) {
        if (si < na) lcomp_s[si] = ls[0];
        if (si + 64 < na) lcomp_s[si + 64] = ls[1];
      }
    }
    __syncthreads();  // B_d : lcomp visible

    // Gumbel for active services only (same per-(q,s) threefry counters);
    // also write prefetched rows to the other buffer.
    if (tid < 128) {
      float gv = -3.0e38f;
      if (tid < na) {
        const int s = act_s[tid];
        unsigned o0, o1;
        threefry2x32(keys_s[2 * t], keys_s[2 * t + 1], 0u,
                     (unsigned)(q * 128 + s), o0, o1);
        const unsigned bits = o0 ^ o1;
        const float f = __uint_as_float((bits >> 9) | 0x3f800000u) - 1.0f;
        const float u = (f > 0.0f) ? f : 1.17549435e-38f;
        gv = lcomp_s[tid] - flog(-flog(u));
      }
      gla_s[tid] = gv;
    }
    if (tid < 144) ((float4*)task_s[nxt])[tid] = pf_task;
    if (tid < 128) {
      gb_s[nxt][tid] = pf_gb;
      mask_s[nxt][tid] = pf_mask;
    }
    __syncthreads();  // B_e : gla visible, next buffers filled

    // wave0: argmax(gla) over compact list; wave1: mx + sumexp over lcomp
    if (tid < 64) {
      float z = gla_s[tid];
      int zi = tid;
      const float z2 = gla_s[tid + 64];
      if (z2 > z) { z = z2; zi = tid + 64; }
#pragma unroll
      for (int o = 32; o > 0; o >>= 1) {
        const float zo = __shfl_xor(z, o, 64);
        const int io = __shfl_xor(zi, o, 64);
        if (zo > z || (zo == z && io < zi)) { z = zo; zi = io; }
      }
      if (tid == 0) {
        kstar_s = zi;
        sidx_s = act_s[zi];
      }
    } else if (tid < 128) {
      const int l2 = tid - 64;
      const float la = (l2 < na) ? lcomp_s[l2] : -3.0e38f;
      const float lb = (l2 + 64 < na) ? lcomp_s[l2 + 64] : -3.0e38f;
      float mx = fmaxf(la, lb);
#pragma unroll
      for (int o = 32; o > 0; o >>= 1) mx = fmaxf(mx, __shfl_xor(mx, o, 64));
      float e = fexp(la - mx) + fexp(lb - mx);
#pragma unroll
      for (int o = 32; o > 0; o >>= 1) e += __shfl_xor(e, o, 64);
      if (l2 == 0) { scal[0] = mx; scal[1] = e; }
    }
    __syncthreads();  // B_f

    // State update: every thread redundantly (keeps ava/tp/rel in registers)
    {
      const int si = sidx_s;
      const float s1v = task_s[cur][64 + 4 * si + 1];
      const float s2v = task_s[cur][64 + 4 * si + 2];
      const float s3v = task_s[cur][64 + 4 * si + 3];
      if (tid == 0) {
        const float s0v = task_s[cur][64 + 4 * si];
        const float prob = fexp(lcomp_s[kstar_s] - scal[0]) / scal[1];
        qos_s[topo * 4 + 0] = s0v + rt;
        qos_s[topo * 4 + 1] = s1v * ava;
        qos_s[topo * 4 + 2] = fminf(s2v, tp);
        qos_s[topo * 4 + 3] = s3v * rel;
        ridx_s[topo] += (float)si;
        rprob_s[topo] += prob;
      }
      ava = s1v * ava;
      tp = fminf(s2v, tp);
      rel = s3v * rel;
    }
    __syncthreads();  // B_final
  }
  if (tid < 64) {
    out[q * 64 + tid] = ridx_s[tid];
    out[Qn * Nn + q * 64 + tid] = rprob_s[tid];
  }
}

// ---------------------------------------------------------------------------
extern "C" void kernel_launch(void* const* d_in, const int* in_sizes, int n_in,
                              void* d_out, int out_size, void* d_ws,
                              size_t ws_size, hipStream_t stream) {
  const float* tasks = (const float*)d_in[0];
  const float* constraints = (const float*)d_in[1];
  const int* masks = (const int*)d_in[2];
  const int* topologicals = (const int*)d_in[3];
  const float* w_init1 = (const float*)d_in[4];
  const float* b_init1 = (const float*)d_in[5];
  const float* w_init2 = (const float*)d_in[6];
  const float* b_init2 = (const float*)d_in[7];
  const float* wq = (const float*)d_in[8];
  const float* bq = (const float*)d_in[9];
  const float* wk = (const float*)d_in[10];
  const float* bk = (const float*)d_in[11];
  const float* wv = (const float*)d_in[12];
  const float* bv = (const float*)d_in[13];
  const float* wo = (const float*)d_in[14];
  const float* bo = (const float*)d_in[15];
  const float* w_node1 = (const float*)d_in[16];
  const float* b_node1 = (const float*)d_in[17];
  const float* w_node2 = (const float*)d_in[18];
  const float* b_node2 = (const float*)d_in[19];
  const float* w_ser1 = (const float*)d_in[20];
  const float* b_ser1 = (const float*)d_in[21];
  const float* w_ser2 = (const float*)d_in[22];
  const float* b_ser2 = (const float*)d_in[23];

  float* ws = (float*)d_ws;
  float* node_emb = ws;                                // Q*N*E; later: gbase
  float* nodes_emb = node_emb + (size_t)Qn * Nn * En;  // Q*N*E (y, then final)
  float* Mbuf = nodes_emb + (size_t)Qn * Nn * En;      // 128*128
  float* dvec = Mbuf + 128 * 128;
  unsigned* keys = (unsigned*)(dvec + 128);            // 128 u32
  float* gbase = node_emb;  // reuse: node_emb dead after gbase_kernel input

  setup_kernel<<<130, 128, 0, stream>>>(w_node2, b_node2, w_ser2, b_ser2, Mbuf,
                                        dvec, keys);
  init_mlp_kernel<<<Qn, 256, 0, stream>>>(tasks, constraints, w_init1, b_init1,
                                          w_init2, b_init2, node_emb);
  mha_kernel<<<Qn, 256, 0, stream>>>(node_emb, wq, bq, wk, bk, wv, bv,
                                     nodes_emb);
  outproj_kernel<<<Qn, 256, 0, stream>>>(node_emb, wo, bo, nodes_emb);
  gbase_kernel<<<Qn, 256, 0, stream>>>(nodes_emb, w_node1, b_node1, gbase);
  scan_kernel<<<Qn, 256, 0, stream>>>(tasks, masks, topologicals, w_node1,
                                      w_ser1, b_ser1, gbase, Mbuf, dvec, keys,
                                      (float*)d_out);
}

// Round 2
// 2069.037 us; speedup vs baseline: 1.1215x; 1.0756x over previous
//
#include <hip/hip_runtime.h>
#include <math.h>

// Problem constants
#define Qn 2048
#define Nn 64
#define Sn 128
#define An 4
#define En 128
#define TASKW 576  // N + 4*S
#define NEGV -1000000000.0f

// ---------------------------------------------------------------------------
// Packed fp32 math (v_pk_fma_f32: 2 x f32 per lane per issue).
// ---------------------------------------------------------------------------
typedef float v2f __attribute__((ext_vector_type(2)));
typedef float v4f __attribute__((ext_vector_type(4)));

__device__ __forceinline__ v2f mkv2(float a, float b) {
  v2f r; r.x = a; r.y = b; return r;
}
__device__ __forceinline__ v2f lo2(v4f v) { v2f r; r.x = v.x; r.y = v.y; return r; }
__device__ __forceinline__ v2f hi2(v4f v) { v2f r; r.x = v.z; r.y = v.w; return r; }
__device__ __forceinline__ void pkfma(v2f& d, v2f a, v2f b) {
  asm("v_pk_fma_f32 %0, %1, %2, %0" : "+v"(d) : "v"(a), "v"(b));
}
__device__ __forceinline__ v2f pkadd(v2f a, v2f b) {
  v2f d; asm("v_pk_add_f32 %0, %1, %2" : "=v"(d) : "v"(a), "v"(b)); return d;
}

// ---------------------------------------------------------------------------
// Threefry-2x32 (20 rounds), matches JAX's threefry2x32_p exactly.
// ---------------------------------------------------------------------------
__device__ __forceinline__ void threefry2x32(unsigned k0, unsigned k1,
                                             unsigned x0, unsigned x1,
                                             unsigned& o0, unsigned& o1) {
  unsigned ks2 = k0 ^ k1 ^ 0x1BD11BDAu;
  x0 += k0; x1 += k1;
#define TFR(r) { x0 += x1; x1 = (x1 << (r)) | (x1 >> (32 - (r))); x1 ^= x0; }
  TFR(13) TFR(15) TFR(26) TFR(6)
  x0 += k1;  x1 += ks2 + 1u;
  TFR(17) TFR(29) TFR(16) TFR(24)
  x0 += ks2; x1 += k0 + 2u;
  TFR(13) TFR(15) TFR(26) TFR(6)
  x0 += k0;  x1 += k1 + 3u;
  TFR(17) TFR(29) TFR(16) TFR(24)
  x0 += k1;  x1 += ks2 + 4u;
  TFR(13) TFR(15) TFR(26) TFR(6)
  x0 += ks2; x1 += k0 + 5u;
#undef TFR
  o0 = x0; o1 = x1;
}

__device__ __forceinline__ float silu_f(float x) {
  return x / (1.0f + expf(-x));
}
__device__ __forceinline__ float fexp(float x) {
  return __builtin_amdgcn_exp2f(x * 1.44269504088896f);
}
__device__ __forceinline__ float fsilu(float x) {
  const float e = __builtin_amdgcn_exp2f(x * -1.44269504088896f);
  return x * __builtin_amdgcn_rcpf(1.0f + e);
}
__device__ __forceinline__ float flog(float x) {
  return __builtin_amdgcn_logf(x) * 0.69314718055995f;
}

// ---------------------------------------------------------------------------
// Setup: M = w_node2 @ w_ser2^T, dvec fold, PRNG keys
// ---------------------------------------------------------------------------
__global__ void setup_kernel(const float* __restrict__ w_node2,
                             const float* __restrict__ b_node2,
                             const float* __restrict__ w_ser2,
                             const float* __restrict__ b_ser2,
                             float* __restrict__ Mbuf, float* __restrict__ dvec,
                             unsigned* __restrict__ keys) {
  const int b = blockIdx.x, t = threadIdx.x;
  if (b < 128) {
    float acc = 0.0f;
    for (int e = 0; e < 128; ++e)
      acc = fmaf(w_node2[b * 128 + e], w_ser2[t * 128 + e], acc);
    Mbuf[b * 128 + t] = acc;
  } else if (b == 128) {
    float acc = 0.0f;
    for (int e = 0; e < 128; ++e)
      acc = fmaf(b_node2[e], w_ser2[t * 128 + e], acc);
    dvec[t] = acc;
  } else {
    if (t < 64) {
      unsigned o0, o1;
      threefry2x32(0u, 1u, 0u, (unsigned)t, o0, o1);
      keys[2 * t + 0] = o0;
      keys[2 * t + 1] = o1;
    }
  }
}

// ---------------------------------------------------------------------------
// K1: node_emb = silu(concat(tasks[:,:, :64], cons) @ w1 + b1) @ w2 + b2
// b128 LDS reads (xr rows 68 floats = 17 v4; sgb rows 128 = 32 v4).
// ---------------------------------------------------------------------------
__global__ __launch_bounds__(256, 2)
void init_mlp_kernel(const float* __restrict__ tasks,
                     const float* __restrict__ cons,
                     const float* __restrict__ w1, const float* __restrict__ b1,
                     const float* __restrict__ w2, const float* __restrict__ b2,
                     float* __restrict__ node_emb) {
  const int q = blockIdx.x, tid = threadIdx.x;
  const int lane = tid & 127, half = tid >> 7;
  __shared__ __align__(16) float xr[2][68];
  __shared__ __align__(16) float sgb[2][128];
  v2f w1p[34], w2p[64];
#pragma unroll
  for (int i = 0; i < 34; ++i)
    w1p[i] = mkv2(w1[(2 * i) * 128 + lane], w1[(2 * i + 1) * 128 + lane]);
#pragma unroll
  for (int j = 0; j < 64; ++j)
    w2p[j] = mkv2(w2[(2 * j) * 128 + lane], w2[(2 * j + 1) * 128 + lane]);
  const float bb1 = b1[lane], bb2 = b2[lane];
  for (int r = 0; r < 64; r += 2) {
    if (tid < 136) {
      const int rr = tid / 68, j = tid - rr * 68;
      xr[rr][j] = (j < 64) ? tasks[(q * 64 + r + rr) * TASKW + j]
                           : cons[q * 4 + (j - 64)];
    }
    __syncthreads();
    v2f gp = mkv2(0.0f, 0.0f);
    const v4f* xr4 = (const v4f*)&xr[half][0];
#pragma unroll
    for (int i = 0; i < 17; ++i) {
      const v4f x = xr4[i];
      pkfma(gp, lo2(x), w1p[2 * i]);
      pkfma(gp, hi2(x), w1p[2 * i + 1]);
    }
    const float g = gp.x + gp.y + bb1;
    sgb[half][lane] = silu_f(g);
    __syncthreads();
    v2f op = mkv2(0.0f, 0.0f);
    const v4f* sgb4 = (const v4f*)&sgb[half][0];
#pragma unroll
    for (int j = 0; j < 32; ++j) {
      const v4f s = sgb4[j];
      pkfma(op, lo2(s), w2p[2 * j]);
      pkfma(op, hi2(s), w2p[2 * j + 1]);
    }
    node_emb[(q * 64 + r + half) * 128 + lane] = op.x + op.y + bb2;
    __syncthreads();
  }
}

// ---------------------------------------------------------------------------
// K2: fused MHA (QKV + scores + softmax + AV), b128 LDS reads throughout.
// Row strides padded to multiples of 4 floats (16B) for ds_read_b128.
// ---------------------------------------------------------------------------
__global__ __launch_bounds__(256, 2)
void mha_kernel(const float* __restrict__ node_emb,
                const float* __restrict__ wq, const float* __restrict__ bq,
                const float* __restrict__ wk, const float* __restrict__ bk,
                const float* __restrict__ wv, const float* __restrict__ bv,
                float* __restrict__ y_out) {
  const int q = blockIdx.x, tid = threadIdx.x;
  __shared__ __align__(16) float xs[64][132];
  __shared__ __align__(16) float qh[64][20];
  __shared__ __align__(16) float kh[64][20];
  __shared__ __align__(16) float vt[16][68];
  __shared__ __align__(16) float pool[3 * 16 * 132];  // wht[3][16][132] U at[64][68]
  float (*wht)[16][132] = (float (*)[16][132])pool;
  float (*at)[68] = (float (*)[68])pool;

  for (int idx = tid; idx < 64 * 32; idx += 256) {
    const int n = idx >> 5, e4 = idx & 31;
    *(v4f*)&xs[n][4 * e4] =
        *(const v4f*)&node_emb[(q * 64 + n) * 128 + 4 * e4];
  }
  __syncthreads();

  const int d16 = tid >> 4;  // 0..15
  const int ng = tid & 15;   // 0..15

  for (int hd = 0; hd < 8; ++hd) {
    for (int idx = tid; idx < 3 * 128 * 16; idx += 256) {
      const int m = idx >> 11, k = (idx >> 4) & 127, d = idx & 15;
      const float* W = (m == 0) ? wq : (m == 1) ? wk : wv;
      wht[m][d][k] = W[k * 128 + hd * 16 + d];
    }
    __syncthreads();

    {
      const float bqv = bq[hd * 16 + d16];
      const float bkv = bk[hd * 16 + d16];
      const float bvv = bv[hd * 16 + d16];
      const v4f* wq4 = (const v4f*)&wht[0][d16][0];
      const v4f* wk4 = (const v4f*)&wht[1][d16][0];
      const v4f* wv4 = (const v4f*)&wht[2][d16][0];
      const v4f* xr0 = (const v4f*)&xs[ng][0];
      const v4f* xr1 = (const v4f*)&xs[ng + 16][0];
      const v4f* xr2 = (const v4f*)&xs[ng + 32][0];
      const v4f* xr3 = (const v4f*)&xs[ng + 48][0];
      v2f aq0 = mkv2(0, 0), aq1 = mkv2(0, 0), aq2 = mkv2(0, 0), aq3 = mkv2(0, 0);
      v2f ak0 = mkv2(0, 0), ak1 = mkv2(0, 0), ak2 = mkv2(0, 0), ak3 = mkv2(0, 0);
      v2f av0 = mkv2(0, 0), av1 = mkv2(0, 0), av2 = mkv2(0, 0), av3 = mkv2(0, 0);
#pragma unroll 4
      for (int kk = 0; kk < 32; ++kk) {
        const v4f wqv = wq4[kk], wkv = wk4[kk], wvv = wv4[kk];
        const v4f x0 = xr0[kk], x1 = xr1[kk], x2 = xr2[kk], x3 = xr3[kk];
        const v2f wqa = lo2(wqv), wqb = hi2(wqv);
        const v2f wka = lo2(wkv), wkb = hi2(wkv);
        const v2f wva = lo2(wvv), wvb = hi2(wvv);
        const v2f x0a = lo2(x0), x0b = hi2(x0);
        const v2f x1a = lo2(x1), x1b = hi2(x1);
        const v2f x2a = lo2(x2), x2b = hi2(x2);
        const v2f x3a = lo2(x3), x3b = hi2(x3);
        pkfma(aq0, x0a, wqa); pkfma(aq0, x0b, wqb);
        pkfma(aq1, x1a, wqa); pkfma(aq1, x1b, wqb);
        pkfma(aq2, x2a, wqa); pkfma(aq2, x2b, wqb);
        pkfma(aq3, x3a, wqa); pkfma(aq3, x3b, wqb);
        pkfma(ak0, x0a, wka); pkfma(ak0, x0b, wkb);
        pkfma(ak1, x1a, wka); pkfma(ak1, x1b, wkb);
        pkfma(ak2, x2a, wka); pkfma(ak2, x2b, wkb);
        pkfma(ak3, x3a, wka); pkfma(ak3, x3b, wkb);
        pkfma(av0, x0a, wva); pkfma(av0, x0b, wvb);
        pkfma(av1, x1a, wva); pkfma(av1, x1b, wvb);
        pkfma(av2, x2a, wva); pkfma(av2, x2b, wvb);
        pkfma(av3, x3a, wva); pkfma(av3, x3b, wvb);
      }
      qh[ng][d16] = fmaxf(aq0.x + aq0.y + bqv, 0.0f);
      qh[ng + 16][d16] = fmaxf(aq1.x + aq1.y + bqv, 0.0f);
      qh[ng + 32][d16] = fmaxf(aq2.x + aq2.y + bqv, 0.0f);
      qh[ng + 48][d16] = fmaxf(aq3.x + aq3.y + bqv, 0.0f);
      kh[ng][d16] = fmaxf(ak0.x + ak0.y + bkv, 0.0f);
      kh[ng + 16][d16] = fmaxf(ak1.x + ak1.y + bkv, 0.0f);
      kh[ng + 32][d16] = fmaxf(ak2.x + ak2.y + bkv, 0.0f);
      kh[ng + 48][d16] = fmaxf(ak3.x + ak3.y + bkv, 0.0f);
      vt[d16][ng] = fmaxf(av0.x + av0.y + bvv, 0.0f);
      vt[d16][ng + 16] = fmaxf(av1.x + av1.y + bvv, 0.0f);
      vt[d16][ng + 32] = fmaxf(av2.x + av2.y + bvv, 0.0f);
      vt[d16][ng + 48] = fmaxf(av3.x + av3.y + bvv, 0.0f);
    }
    __syncthreads();

    {
      const int n = tid >> 2, mg = tid & 3;
      v4f qv[4];
      const v4f* qrow = (const v4f*)&qh[n][0];
#pragma unroll
      for (int kk = 0; kk < 4; ++kk) qv[kk] = qrow[kk];
#pragma unroll 4
      for (int jj = 0; jj < 16; ++jj) {
        const int m = mg + 4 * jj;
        const v4f* krow = (const v4f*)&kh[m][0];
        v2f accp = mkv2(0.0f, 0.0f);
#pragma unroll
        for (int kk = 0; kk < 4; ++kk) {
          const v4f kv = krow[kk];
          pkfma(accp, lo2(qv[kk]), lo2(kv));
          pkfma(accp, hi2(qv[kk]), hi2(kv));
        }
        at[n][m] = (accp.x + accp.y) * 0.25f;
      }
    }
    __syncthreads();

    {
      const int r = tid >> 2, p = tid & 3;
      const v4f* arow = (const v4f*)&at[r][p * 16];
      v4f av[4];
#pragma unroll
      for (int u = 0; u < 4; ++u) av[u] = arow[u];
      float mx = -1e30f;
#pragma unroll
      for (int u = 0; u < 4; ++u) {
        mx = fmaxf(mx, fmaxf(fmaxf(av[u].x, av[u].y), fmaxf(av[u].z, av[u].w)));
      }
      mx = fmaxf(mx, __shfl_xor(mx, 1, 64));
      mx = fmaxf(mx, __shfl_xor(mx, 2, 64));
      float s = 0.0f;
#pragma unroll
      for (int u = 0; u < 4; ++u) {
        av[u].x = fexp(av[u].x - mx); av[u].y = fexp(av[u].y - mx);
        av[u].z = fexp(av[u].z - mx); av[u].w = fexp(av[u].w - mx);
        s += av[u].x + av[u].y + av[u].z + av[u].w;
      }
      s += __shfl_xor(s, 1, 64);
      s += __shfl_xor(s, 2, 64);
      const float rs = __builtin_amdgcn_rcpf(s);
      v4f* wrow = (v4f*)&at[r][p * 16];
#pragma unroll
      for (int u = 0; u < 4; ++u) {
        av[u].x *= rs; av[u].y *= rs; av[u].z *= rs; av[u].w *= rs;
        wrow[u] = av[u];
      }
    }
    __syncthreads();

    {
      const int dd = tid & 15, ngr = tid >> 4;
      const v4f* vrow = (const v4f*)&vt[dd][0];
      const v4f* ar0 = (const v4f*)&at[ngr][0];
      const v4f* ar1 = (const v4f*)&at[ngr + 16][0];
      const v4f* ar2 = (const v4f*)&at[ngr + 32][0];
      const v4f* ar3 = (const v4f*)&at[ngr + 48][0];
      v2f ac0 = mkv2(0, 0), ac1 = mkv2(0, 0), ac2 = mkv2(0, 0), ac3 = mkv2(0, 0);
#pragma unroll 4
      for (int kk = 0; kk < 16; ++kk) {
        const v4f vv = vrow[kk];
        const v2f va = lo2(vv), vb = hi2(vv);
        const v4f a0 = ar0[kk], a1 = ar1[kk], a2 = ar2[kk], a3 = ar3[kk];
        pkfma(ac0, lo2(a0), va); pkfma(ac0, hi2(a0), vb);
        pkfma(ac1, lo2(a1), va); pkfma(ac1, hi2(a1), vb);
        pkfma(ac2, lo2(a2), va); pkfma(ac2, hi2(a2), vb);
        pkfma(ac3, lo2(a3), va); pkfma(ac3, hi2(a3), vb);
      }
      y_out[(q * 64 + ngr) * 128 + hd * 16 + dd] = ac0.x + ac0.y;
      y_out[(q * 64 + ngr + 16) * 128 + hd * 16 + dd] = ac1.x + ac1.y;
      y_out[(q * 64 + ngr + 32) * 128 + hd * 16 + dd] = ac2.x + ac2.y;
      y_out[(q * 64 + ngr + 48) * 128 + hd * 16 + dd] = ac3.x + ac3.y;
    }
    __syncthreads();
  }
}

// ---------------------------------------------------------------------------
// K3 (fused): nodes = relu(y @ wo + bo) + resid; gbase = nodes @ w_node1 + b_node1
// Intermediate `nodes` lives in registers then overwrites the ys LDS tile;
// no global round-trip of nodes_emb at all.
// ---------------------------------------------------------------------------
__global__ __launch_bounds__(256, 2)
void outgb_kernel(const float* __restrict__ resid, const float* __restrict__ y,
                  const float* __restrict__ wo, const float* __restrict__ bo,
                  const float* __restrict__ w_node1,
                  const float* __restrict__ b_node1,
                  float* __restrict__ gbase) {
  const int q = blockIdx.x, tid = threadIdx.x;
  __shared__ __align__(16) float ys[64][132];
  __shared__ __align__(16) float wot[32][132];
  for (int idx = tid; idx < 64 * 32; idx += 256) {
    const int n = idx >> 5, e4 = idx & 31;
    *(v4f*)&ys[n][4 * e4] = *(const v4f*)&y[(q * 64 + n) * 128 + 4 * e4];
  }
  const int cg = tid & 15, ngr = tid >> 4;
  float nodes[4][8];  // [n-group][tile*2 + {0,1}]

#pragma unroll
  for (int tile = 0; tile < 4; ++tile) {
    const int c0 = 32 * tile;
    __syncthreads();
    for (int idx = tid; idx < 32 * 128; idx += 256) {
      const int k = idx >> 5, c = idx & 31;
      wot[c][k] = wo[k * 128 + c0 + c];
    }
    __syncthreads();
    const int c = c0 + 2 * cg;
    const v4f* w0 = (const v4f*)&wot[2 * cg][0];
    const v4f* w1 = (const v4f*)&wot[2 * cg + 1][0];
    const v4f* yr0 = (const v4f*)&ys[ngr][0];
    const v4f* yr1 = (const v4f*)&ys[ngr + 16][0];
    const v4f* yr2 = (const v4f*)&ys[ngr + 32][0];
    const v4f* yr3 = (const v4f*)&ys[ngr + 48][0];
    v2f a00 = mkv2(0, 0), a01 = mkv2(0, 0), a10 = mkv2(0, 0), a11 = mkv2(0, 0);
    v2f a20 = mkv2(0, 0), a21 = mkv2(0, 0), a30 = mkv2(0, 0), a31 = mkv2(0, 0);
#pragma unroll 4
    for (int kk = 0; kk < 32; ++kk) {
      const v4f wv0 = w0[kk], wv1 = w1[kk];
      const v2f w0a = lo2(wv0), w0b = hi2(wv0);
      const v2f w1a = lo2(wv1), w1b = hi2(wv1);
      const v4f x0 = yr0[kk], x1 = yr1[kk], x2 = yr2[kk], x3 = yr3[kk];
      pkfma(a00, lo2(x0), w0a); pkfma(a00, hi2(x0), w0b);
      pkfma(a01, lo2(x0), w1a); pkfma(a01, hi2(x0), w1b);
      pkfma(a10, lo2(x1), w0a); pkfma(a10, hi2(x1), w0b);
      pkfma(a11, lo2(x1), w1a); pkfma(a11, hi2(x1), w1b);
      pkfma(a20, lo2(x2), w0a); pkfma(a20, hi2(x2), w0b);
      pkfma(a21, lo2(x2), w1a); pkfma(a21, hi2(x2), w1b);
      pkfma(a30, lo2(x3), w0a); pkfma(a30, hi2(x3), w0b);
      pkfma(a31, lo2(x3), w1a); pkfma(a31, hi2(x3), w1b);
    }
    const float b0v = bo[c], b1v = bo[c + 1];
#define PROJ_EMIT(J, A0, A1)                                                  \
    {                                                                         \
      const int n = ngr + 16 * J;                                             \
      const float2 res = *(const float2*)&resid[(q * 64 + n) * 128 + c];      \
      nodes[J][2 * tile] = fmaxf(A0.x + A0.y + b0v, 0.0f) + res.x;            \
      nodes[J][2 * tile + 1] = fmaxf(A1.x + A1.y + b1v, 0.0f) + res.y;        \
    }
    PROJ_EMIT(0, a00, a01)
    PROJ_EMIT(1, a10, a11)
    PROJ_EMIT(2, a20, a21)
    PROJ_EMIT(3, a30, a31)
#undef PROJ_EMIT
  }
  __syncthreads();
  // overwrite ys with nodes
#pragma unroll
  for (int j = 0; j < 4; ++j) {
    const int n = ngr + 16 * j;
#pragma unroll
    for (int tile = 0; tile < 4; ++tile) {
      *(float2*)&ys[n][32 * tile + 2 * cg] =
          make_float2(nodes[j][2 * tile], nodes[j][2 * tile + 1]);
    }
  }

#pragma unroll
  for (int tile = 0; tile < 4; ++tile) {
    const int c0 = 32 * tile;
    __syncthreads();
    for (int idx = tid; idx < 32 * 128; idx += 256) {
      const int k = idx >> 5, c = idx & 31;
      wot[c][k] = w_node1[k * 128 + c0 + c];
    }
    __syncthreads();
    const int c = c0 + 2 * cg;
    const v4f* w0 = (const v4f*)&wot[2 * cg][0];
    const v4f* w1 = (const v4f*)&wot[2 * cg + 1][0];
    const v4f* yr0 = (const v4f*)&ys[ngr][0];
    const v4f* yr1 = (const v4f*)&ys[ngr + 16][0];
    const v4f* yr2 = (const v4f*)&ys[ngr + 32][0];
    const v4f* yr3 = (const v4f*)&ys[ngr + 48][0];
    v2f a00 = mkv2(0, 0), a01 = mkv2(0, 0), a10 = mkv2(0, 0), a11 = mkv2(0, 0);
    v2f a20 = mkv2(0, 0), a21 = mkv2(0, 0), a30 = mkv2(0, 0), a31 = mkv2(0, 0);
#pragma unroll 4
    for (int kk = 0; kk < 32; ++kk) {
      const v4f wv0 = w0[kk], wv1 = w1[kk];
      const v2f w0a = lo2(wv0), w0b = hi2(wv0);
      const v2f w1a = lo2(wv1), w1b = hi2(wv1);
      const v4f x0 = yr0[kk], x1 = yr1[kk], x2 = yr2[kk], x3 = yr3[kk];
      pkfma(a00, lo2(x0), w0a); pkfma(a00, hi2(x0), w0b);
      pkfma(a01, lo2(x0), w1a); pkfma(a01, hi2(x0), w1b);
      pkfma(a10, lo2(x1), w0a); pkfma(a10, hi2(x1), w0b);
      pkfma(a11, lo2(x1), w1a); pkfma(a11, hi2(x1), w1b);
      pkfma(a20, lo2(x2), w0a); pkfma(a20, hi2(x2), w0b);
      pkfma(a21, lo2(x2), w1a); pkfma(a21, hi2(x2), w1b);
      pkfma(a30, lo2(x3), w0a); pkfma(a30, hi2(x3), w0b);
      pkfma(a31, lo2(x3), w1a); pkfma(a31, hi2(x3), w1b);
    }
    const float b0v = b_node1[c], b1v = b_node1[c + 1];
#define GB_EMIT(J, A0, A1)                                                    \
    {                                                                         \
      const int n = ngr + 16 * J;                                             \
      float2 o;                                                               \
      o.x = A0.x + A0.y + b0v;                                                \
      o.y = A1.x + A1.y + b1v;                                                \
      *(float2*)&gbase[(q * 64 + n) * 128 + c] = o;                           \
    }
    GB_EMIT(0, a00, a01)
    GB_EMIT(1, a10, a11)
    GB_EMIT(2, a20, a21)
    GB_EMIT(3, a30, a31)
#undef GB_EMIT
  }
}

// ---------------------------------------------------------------------------
// K4: 64-step scan, one workgroup per q. DS-count-minimized:
//  - logits: 8 threads/service-group x 4 services/group; weights for each
//    h-pair packed as 3 x b128 {w01,w23,bias|uu}, read once per group and
//    reused over 4 services; wave-level skip of inactive slot ranges.
//  - matvec reads sg via b128; qw rows packed as one b128.
//  - per-wave redundant argmax (removes one barrier + scal round-trip).
//  - dead qos columns dropped (only col 0 is ever read -> qr_s).
// ---------------------------------------------------------------------------
__global__ __launch_bounds__(256, 3)
void scan_kernel(const float* __restrict__ tasks, const int* __restrict__ masks,
                 const int* __restrict__ topologicals,
                 const float* __restrict__ w_node1,
                 const float* __restrict__ w_ser1,
                 const float* __restrict__ b_ser1,
                 const float* __restrict__ gbase,
                 const float* __restrict__ Mbuf, const float* __restrict__ dvec,
                 const unsigned* __restrict__ keys, float* __restrict__ out) {
  const int q = blockIdx.x, tid = threadIdx.x;
  const int lane = tid & 127, half = tid >> 7;
  const int wl = tid & 63;   // lane within wave
  const int wave = tid >> 6;

  __shared__ __align__(16) float task_s[2][TASKW];
  __shared__ __align__(16) float gb_s[2][128];
  __shared__ int mask_s[2][128];
  __shared__ int topo_s[64];
  __shared__ __align__(16) float sg[128];
  __shared__ __align__(16) v2f wfull_s[64][6];  // {w0,w1,w2,w3,bp,up} per h-pair
  __shared__ __align__(16) float red[256];
  __shared__ float lcomp_s[128];  // logits, compact (active) order
  __shared__ float gla_s[128];    // gumbel-perturbed, compact order
  __shared__ int act_s[128];      // active service indices
  __shared__ float qr_s[64];      // qos col 0 (the only live column)
  __shared__ float ridx_s[64], rprob_s[64];
  __shared__ __align__(16) v4f qw4_s[128];  // w_node1 rows 128..131 packed
  __shared__ __align__(16) float dvs[128];
  __shared__ unsigned keys_s[128];
  __shared__ int na_s;

  v2f Mr2[32];
#pragma unroll
  for (int j = 0; j < 32; ++j)
    Mr2[j] = mkv2(Mbuf[(half * 64 + 2 * j) * 128 + lane],
                  Mbuf[(half * 64 + 2 * j + 1) * 128 + lane]);

  if (tid < 64) {
    topo_s[tid] = topologicals[q * 64 + tid];
    const int j = tid;
#pragma unroll
    for (int c = 0; c < 4; ++c)
      wfull_s[j][c] =
          mkv2(w_ser1[c * 128 + 2 * j], w_ser1[c * 128 + 2 * j + 1]);
    wfull_s[j][4] = mkv2(b_ser1[2 * j], b_ser1[2 * j + 1]);
    qr_s[tid] = 3.0f;
    ridx_s[tid] = 0.0f;
    rprob_s[tid] = 0.0f;
  }
  if (tid < 128) {
    dvs[tid] = dvec[tid];
    keys_s[tid] = keys[tid];
    v4f qp;
    qp.x = w_node1[128 * 128 + tid];
    qp.y = w_node1[129 * 128 + tid];
    qp.z = w_node1[130 * 128 + tid];
    qp.w = w_node1[131 * 128 + tid];
    qw4_s[tid] = qp;
  }
  float ava = 1.0f, tp = 3.0f, rel = 1.0f;  // per-thread redundant state
  __syncthreads();

  // Prologue: stage step 0 into buffer 0
  {
    const int topo0 = topo_s[63];
    if (tid < 144)
      ((float4*)task_s[0])[tid] =
          ((const float4*)(tasks + (size_t)(q * 64 + topo0) * TASKW))[tid];
    if (tid < 128) {
      gb_s[0][tid] = gbase[(q * 64 + topo0) * 128 + tid];
      mask_s[0][tid] = masks[(q * 64 + topo0) * 128 + tid];
    }
  }
  __syncthreads();

  for (int t = 0; t < 64; ++t) {
    const int cur = t & 1, nxt = cur ^ 1;
    const int topo = topo_s[63 - t];

    // Phase 1: waves 0/1 compute rt; wave 2 compacts active services.
    float rt = 0.0f;
    if (wave < 2) {
      float p = task_s[cur][wl] * qr_s[wl];
#pragma unroll
      for (int o = 32; o > 0; o >>= 1) p = fmaxf(p, __shfl_xor(p, o, 64));
      rt = p;
    } else if (wave == 2) {
      const int m0 = mask_s[cur][wl] != 0;
      const int m1 = mask_s[cur][wl + 64] != 0;
      const unsigned long long b0 = __ballot(m0);
      const unsigned long long b1 = __ballot(m1);
      const unsigned long long lt = (1ull << wl) - 1ull;
      const int c0 = __popcll(b0);
      if (m0) act_s[__popcll(b0 & lt)] = wl;
      if (m1) act_s[c0 + __popcll(b1 & lt)] = wl + 64;
      if (wl == 0) na_s = c0 + __popcll(b1);
    }
    if (tid < 128) {
      const v4f qp = qw4_s[tid];
      float g = gb_s[cur][tid];
      g = fmaf(rt, qp.x, g);
      g = fmaf(ava, qp.y, g);
      g = fmaf(tp, qp.z, g);
      g = fmaf(rel, qp.w, g);
      sg[tid] = fsilu(g);
    }
    __syncthreads();  // B_a : sg, act, na visible
    const int na = na_s;

    // u = silu(g) @ M + dvec (split partials, b128 sg reads)
    {
      v2f accp = mkv2(0.0f, 0.0f);
      const v4f* sgp = (const v4f*)sg + half * 16;
#pragma unroll
      for (int j = 0; j < 16; ++j) {
        const v4f x = sgp[j];
        pkfma(accp, lo2(x), Mr2[2 * j]);
        pkfma(accp, hi2(x), Mr2[2 * j + 1]);
      }
      red[tid] = accp.x + accp.y;
    }
    __syncthreads();  // B_b
    if (tid < 64) {
      const v2f r0 = *(const v2f*)&red[2 * tid];
      const v2f r1 = *(const v2f*)&red[2 * tid + 128];
      const v2f dv = *(const v2f*)&dvs[2 * tid];
      wfull_s[tid][5] = pkadd(pkadd(r0, r1), dv);
    }
    __syncthreads();  // B_c : up visible

    // Prefetch next step's rows (issue early; lands in regs)
    float4 pf_task;
    float pf_gb;
    int pf_mask;
    {
      const int tn = (t < 63) ? t + 1 : 63;
      const int ntopo = topo_s[63 - tn];
      if (tid < 144)
        pf_task =
            ((const float4*)(tasks + (size_t)(q * 64 + ntopo) * TASKW))[tid];
      if (tid < 128) {
        pf_gb = gbase[(q * 64 + ntopo) * 128 + tid];
        pf_mask = masks[(q * 64 + ntopo) * 128 + tid];
      }
    }

    // Compact logits: group of 8 threads handles 4 services; each thread
    // covers 8 h-pairs (j = o + 8*jj); weights read once, reused 4x.
    {
      const int g8 = tid >> 3, o = tid & 7;
      const int sl0 = 4 * g8;
      if (wave * 32 < na) {
        const int s0 = (sl0 + 0 < na) ? act_s[sl0 + 0] : 0;
        const int s1 = (sl0 + 1 < na) ? act_s[sl0 + 1] : 0;
        const int s2 = (sl0 + 2 < na) ? act_s[sl0 + 2] : 0;
        const int s3 = (sl0 + 3 < na) ? act_s[sl0 + 3] : 0;
        const float4 svA = *(const float4*)&task_s[cur][64 + 4 * s0];
        const float4 svB = *(const float4*)&task_s[cur][64 + 4 * s1];
        const float4 svC = *(const float4*)&task_s[cur][64 + 4 * s2];
        const float4 svD = *(const float4*)&task_s[cur][64 + 4 * s3];
        const v2f A0 = mkv2(svA.x, svA.x), A1 = mkv2(svA.y, svA.y),
                  A2 = mkv2(svA.z, svA.z), A3 = mkv2(svA.w, svA.w);
        const v2f B0 = mkv2(svB.x, svB.x), B1 = mkv2(svB.y, svB.y),
                  B2 = mkv2(svB.z, svB.z), B3 = mkv2(svB.w, svB.w);
        const v2f C0 = mkv2(svC.x, svC.x), C1 = mkv2(svC.y, svC.y),
                  C2 = mkv2(svC.z, svC.z), C3 = mkv2(svC.w, svC.w);
        const v2f D0 = mkv2(svD.x, svD.x), D1 = mkv2(svD.y, svD.y),
                  D2 = mkv2(svD.z, svD.z), D3 = mkv2(svD.w, svD.w);
        v2f ac0 = mkv2(0, 0), ac1 = mkv2(0, 0), ac2 = mkv2(0, 0),
            ac3 = mkv2(0, 0);
        const v4f* wp = (const v4f*)&wfull_s[0][0];
#pragma unroll
        for (int jj = 0; jj < 8; ++jj) {
          const int j = o + 8 * jj;
          const v4f wA = wp[3 * j], wB = wp[3 * j + 1], wC = wp[3 * j + 2];
          const v2f w0 = lo2(wA), w1 = hi2(wA);
          const v2f w2 = lo2(wB), w3 = hi2(wB);
          const v2f bp = lo2(wC), up = hi2(wC);
#define SRV(AC, X0, X1, X2, X3)                                               \
          {                                                                   \
            v2f p = bp;                                                       \
            pkfma(p, X0, w0); pkfma(p, X1, w1);                               \
            pkfma(p, X2, w2); pkfma(p, X3, w3);                               \
            const float ex =                                                  \
                __builtin_amdgcn_exp2f(p.x * -1.44269504088896f);             \
            const float ey =                                                  \
                __builtin_amdgcn_exp2f(p.y * -1.44269504088896f);             \
            const float rx = __builtin_amdgcn_rcpf(1.0f + ex);                \
            const float ry = __builtin_amdgcn_rcpf(1.0f + ey);                \
            pkfma(AC, mkv2(p.x * rx, p.y * ry), up);                          \
          }
          SRV(ac0, A0, A1, A2, A3)
          SRV(ac1, B0, B1, B2, B3)
          SRV(ac2, C0, C1, C2, C3)
          SRV(ac3, D0, D1, D2, D3)
#undef SRV
        }
        float l0 = ac0.x + ac0.y, l1 = ac1.x + ac1.y;
        float l2 = ac2.x + ac2.y, l3 = ac3.x + ac3.y;
        l0 += __shfl_xor(l0, 1, 64); l0 += __shfl_xor(l0, 2, 64);
        l0 += __shfl_xor(l0, 4, 64);
        l1 += __shfl_xor(l1, 1, 64); l1 += __shfl_xor(l1, 2, 64);
        l1 += __shfl_xor(l1, 4, 64);
        l2 += __shfl_xor(l2, 1, 64); l2 += __shfl_xor(l2, 2, 64);
        l2 += __shfl_xor(l2, 4, 64);
        l3 += __shfl_xor(l3, 1, 64); l3 += __shfl_xor(l3, 2, 64);
        l3 += __shfl_xor(l3, 4, 64);
        if (o == 0) {
          if (sl0 + 3 < na) {
            *(float4*)&lcomp_s[sl0] = make_float4(l0, l1, l2, l3);
          } else {
            if (sl0 + 0 < na) lcomp_s[sl0 + 0] = l0;
            if (sl0 + 1 < na) lcomp_s[sl0 + 1] = l1;
            if (sl0 + 2 < na) lcomp_s[sl0 + 2] = l2;
          }
        }
      }
    }
    __syncthreads();  // B_d : lcomp visible

    // Gumbel for active services; also land prefetched rows.
    if (tid < 128) {
      float gv = -3.0e38f;
      if (tid < na) {
        const int s = act_s[tid];
        unsigned o0, o1;
        threefry2x32(keys_s[2 * t], keys_s[2 * t + 1], 0u,
                     (unsigned)(q * 128 + s), o0, o1);
        const unsigned bits = o0 ^ o1;
        const float f = __uint_as_float((bits >> 9) | 0x3f800000u) - 1.0f;
        const float u = (f > 0.0f) ? f : 1.17549435e-38f;
        gv = lcomp_s[tid] - flog(-flog(u));
      }
      gla_s[tid] = gv;
    }
    if (tid < 144) ((float4*)task_s[nxt])[tid] = pf_task;
    if (tid < 128) {
      gb_s[nxt][tid] = pf_gb;
      mask_s[nxt][tid] = pf_mask;
    }
    __syncthreads();  // B_e : gla visible, next buffers staged

    // Per-wave redundant argmax (identical inputs -> identical result);
    // wave 3 additionally computes softmax normalizer + rprob.
    int si, kstar;
    {
      float z = gla_s[wl];
      int zi = wl;
      const float z2 = gla_s[wl + 64];
      if (z2 > z) { z = z2; zi = wl + 64; }
#pragma unroll
      for (int o = 32; o > 0; o >>= 1) {
        const float zo = __shfl_xor(z, o, 64);
        const int io = __shfl_xor(zi, o, 64);
        if (zo > z || (zo == z && io < zi)) { z = zo; zi = io; }
      }
      kstar = zi;
      si = act_s[zi];
    }
    if (wave == 3) {
      const float la = (wl < na) ? lcomp_s[wl] : -3.0e38f;
      const float lb = (wl + 64 < na) ? lcomp_s[wl + 64] : -3.0e38f;
      float mx = fmaxf(la, lb);
#pragma unroll
      for (int o = 32; o > 0; o >>= 1) mx = fmaxf(mx, __shfl_xor(mx, o, 64));
      float e = fexp(la - mx) + fexp(lb - mx);
#pragma unroll
      for (int o = 32; o > 0; o >>= 1) e += __shfl_xor(e, o, 64);
      if (wl == 0)
        rprob_s[topo] += fexp(lcomp_s[kstar] - mx) * __builtin_amdgcn_rcpf(e);
    }
    // State update: every thread redundantly (ava/tp/rel in registers)
    {
      const float s1v = task_s[cur][64 + 4 * si + 1];
      const float s2v = task_s[cur][64 + 4 * si + 2];
      const float s3v = task_s[cur][64 + 4 * si + 3];
      if (tid == 0) {
        const float s0v = task_s[cur][64 + 4 * si];
        qr_s[topo] = s0v + rt;
        ridx_s[topo] += (float)si;
      }
      ava = s1v * ava;
      tp = fminf(s2v, tp);
      rel = s3v * rel;
    }
    __syncthreads();  // B_final
  }
  if (tid < 64) {
    out[q * 64 + tid] = ridx_s[tid];
    out[Qn * Nn + q * 64 + tid] = rprob_s[tid];
  }
}

// ---------------------------------------------------------------------------
extern "C" void kernel_launch(void* const* d_in, const int* in_sizes, int n_in,
                              void* d_out, int out_size, void* d_ws,
                              size_t ws_size, hipStream_t stream) {
  const float* tasks = (const float*)d_in[0];
  const float* constraints = (const float*)d_in[1];
  const int* masks = (const int*)d_in[2];
  const int* topologicals = (const int*)d_in[3];
  const float* w_init1 = (const float*)d_in[4];
  const float* b_init1 = (const float*)d_in[5];
  const float* w_init2 = (const float*)d_in[6];
  const float* b_init2 = (const float*)d_in[7];
  const float* wq = (const float*)d_in[8];
  const float* bq = (const float*)d_in[9];
  const float* wk = (const float*)d_in[10];
  const float* bk = (const float*)d_in[11];
  const float* wv = (const float*)d_in[12];
  const float* bv = (const float*)d_in[13];
  const float* wo = (const float*)d_in[14];
  const float* bo = (const float*)d_in[15];
  const float* w_node1 = (const float*)d_in[16];
  const float* b_node1 = (const float*)d_in[17];
  const float* w_node2 = (const float*)d_in[18];
  const float* b_node2 = (const float*)d_in[19];
  const float* w_ser1 = (const float*)d_in[20];
  const float* b_ser1 = (const float*)d_in[21];
  const float* w_ser2 = (const float*)d_in[22];
  const float* b_ser2 = (const float*)d_in[23];

  float* ws = (float*)d_ws;
  float* node_emb = ws;                             // Q*N*E; reused as gbase
  float* ybuf = node_emb + (size_t)Qn * Nn * En;    // Q*N*E (mha output)
  float* Mbuf = ybuf + (size_t)Qn * Nn * En;        // 128*128
  float* dvec = Mbuf + 128 * 128;
  unsigned* keys = (unsigned*)(dvec + 128);         // 128 u32
  float* gbase = node_emb;  // safe: per-block, resid reads precede gbase writes

  setup_kernel<<<130, 128, 0, stream>>>(w_node2, b_node2, w_ser2, b_ser2, Mbuf,
                                        dvec, keys);
  init_mlp_kernel<<<Qn, 256, 0, stream>>>(tasks, constraints, w_init1, b_init1,
                                          w_init2, b_init2, node_emb);
  mha_kernel<<<Qn, 256, 0, stream>>>(node_emb, wq, bq, wk, bk, wv, bv, ybuf);
  outgb_kernel<<<Qn, 256, 0, stream>>>(node_emb, ybuf, wo, bo, w_node1,
                                       b_node1, gbase);
  scan_kernel<<<Qn, 256, 0, stream>>>(tasks, masks, topologicals, w_node1,
                                      w_ser1, b_ser1, gbase, Mbuf, dvec, keys,
                                      (float*)d_out);
}